// Round 4
// baseline (22843.315 us; speedup 1.0000x reference)
//
#include <hip/hip_runtime.h>
#include <math.h>

namespace {

constexpr int B = 256, T = 64, ACTN = 6, EMB = 1024;
constexpr int S = 32, DD = 32, SFN = 1024;   // stoch groups, classes, flat
constexpr int DET = 600, HID = 600;
constexpr int OUTF = 4 * SFN + DET;          // 4696
constexpr int KC = 60;                       // LDS chunk rows (divides 600)

__device__ __forceinline__ float elu1(float x) { return x > 0.f ? x : expm1f(x); }
__device__ __forceinline__ float sigm(float x) { return 1.f / (1.f + expf(-x)); }

// Single-use-slot grid barrier with explicit agent-scope fences (cross-XCD safe).
// Each slot is used exactly once per kernel run; bar[] is zeroed before launch.
__device__ __forceinline__ void gridBar(unsigned* bar, int slot, unsigned nblk) {
    __syncthreads();
    if (threadIdx.x == 0) {
        __threadfence();                         // release: L2 writeback to coherence point
        atomicAdd(&bar[slot], 1u);               // device-scope
        while (__hip_atomic_load(&bar[slot], __ATOMIC_RELAXED, __HIP_MEMORY_SCOPE_AGENT) < nblk) {
            __builtin_amdgcn_s_sleep(2);
        }
        __threadfence();                         // acquire: invalidate stale L1/L2 lines
    }
    __syncthreads();
}

// ---------------- weight prep ----------------
// WB2[p][k][6] = {z,r,h for j=2p ; z,r,h for j=2p+1}; k<600 from Wx, k>=600 from Wh.
__global__ void kWB2(const float* __restrict__ Wx, const float* __restrict__ Wh,
                     float* __restrict__ WB2) {
    int p = blockIdx.x;  // 0..299
    int j0 = 2 * p, j1 = 2 * p + 1;
    for (int k = threadIdx.x; k < 1200; k += blockDim.x) {
        const float* src = (k < 600) ? (Wx + (size_t)k * 1800) : (Wh + (size_t)(k - 600) * 1800);
        float* d = WB2 + ((size_t)p * 1200 + k) * 6;
        d[0] = src[j0]; d[1] = src[600 + j0]; d[2] = src[1200 + j0];
        d[3] = src[j1]; d[4] = src[600 + j1]; d[5] = src[1200 + j1];
    }
}

// WC2[p][k][2] : j-pair (2p,2p+1) of 1200-j space; j<600 -> W_img2 col j, else W_obs1 col j-600.
__global__ void kWC2(const float* __restrict__ W2, const float* __restrict__ Wo1,
                     float* __restrict__ WC2) {
    int p = blockIdx.x;  // 0..599
    int j0 = 2 * p, j1 = j0 + 1;
    for (int k = threadIdx.x; k < 600; k += blockDim.x) {
        float v0 = (j0 < 600) ? W2[(size_t)k * 600 + j0] : Wo1[(size_t)k * 600 + (j0 - 600)];
        float v1 = (j1 < 600) ? W2[(size_t)k * 600 + j1] : Wo1[(size_t)k * 600 + (j1 - 600)];
        float* d = WC2 + ((size_t)p * 600 + k) * 2;
        d[0] = v0; d[1] = v1;
    }
}

// WD[j][k] : j<1024 -> W_img5[k][j] ; else W_obs3[k][j-1024]
__global__ void kWD(const float* __restrict__ W5, const float* __restrict__ Wo3,
                    float* __restrict__ WDm) {
    int k = blockIdx.x;  // 0..599
    for (int j = threadIdx.x; j < 2048; j += blockDim.x) {
        float v = (j < 1024) ? W5[(size_t)k * 1024 + j] : Wo3[(size_t)k * 1024 + (j - 1024)];
        WDm[(size_t)j * 600 + k] = v;
    }
}

// ---------------- embed precompute ----------------
__global__ __launch_bounds__(512) void kPemb(const float* __restrict__ embed,
                                             const float* __restrict__ Wo1,
                                             const float* __restrict__ bo1,
                                             float* __restrict__ embPre) {
    int bid = blockIdx.x;
    int jg = bid % 10;
    int r = bid / 10;
    int bg = r & 3;
    int t = r >> 2;
    int tid = threadIdx.x;
    int lane = tid & 63;
    int wid = __builtin_amdgcn_readfirstlane(tid >> 6);
    int b0 = bg * 64;
    int j0 = jg * 64 + wid * 8;
    bool active = (j0 < 600);
    __shared__ float tile[64 * 129];
    float acc[8] = {0, 0, 0, 0, 0, 0, 0, 0};
    for (int kc = 0; kc < EMB; kc += 128) {
        __syncthreads();
        for (int ii = tid; ii < 64 * 128; ii += 512) {
            int i = ii >> 7, k = ii & 127;
            tile[i * 129 + k] = embed[((size_t)(b0 + i) * T + t) * EMB + kc + k];
        }
        __syncthreads();
        if (active) {
            const float* wbase = Wo1 + (size_t)(600 + kc) * 600 + j0;
#pragma unroll 4
            for (int k = 0; k < 128; ++k) {
                float v = tile[lane * 129 + k];
                float4 wa = *(const float4*)(wbase + (size_t)k * 600);
                float4 wb = *(const float4*)(wbase + (size_t)k * 600 + 4);
                acc[0] += v * wa.x; acc[1] += v * wa.y; acc[2] += v * wa.z; acc[3] += v * wa.w;
                acc[4] += v * wb.x; acc[5] += v * wb.y; acc[6] += v * wb.z; acc[7] += v * wb.w;
            }
        }
    }
    if (active) {
#pragma unroll
        for (int c = 0; c < 8; ++c)
            embPre[((size_t)t * 600 + j0 + c) * B + b0 + lane] = acc[c] + bo1[j0 + c];
    }
}

// ---------------- the persistent fused kernel ----------------
// Grid 320 x 512 (plain launch; 2 blocks/CU x 256 CU = 512 resident slots >= 320).
__global__ __launch_bounds__(512, 4) void kMain(
    const float* act, const float* W1, const float* b1,
    const float* WB2, const float* b_in, const float* b_rec,
    const float* WC2, const float* b2, const float* embPre,
    const float* WDm, const float* b5, const float* bo3,
    const float* gImg, const float* gObs,
    float* xT, float* dA, float* dB, float* yoT, int* idxB,
    unsigned* bar, float* out) {
    int bid = blockIdx.x;
    int tid = threadIdx.x;
    int lane = tid & 63;
    int ws = __builtin_amdgcn_readfirstlane(tid >> 6);  // 0..7
    unsigned nblk = gridDim.x;

    // B/C role decode
    int xcd = bid & 7, q = bid >> 3;
    int jgl = q % 10, rgBC = q / 10;
    int jg = xcd + 8 * jgl;
    bool bcActive = (jg < 75);
    int b0BC = rgBC * 64;
    // D role decode
    bool dActive = (bid < 256);
    int sg = (bid & 7) + 8 * ((bid >> 3) & 7);
    int rgD = bid >> 6;            // 0..3 for bid<256
    int postD = (sg >= 32) ? 1 : 0;
    int sD = postD ? sg - 32 : sg;
    int b0D = rgD * 64;

    __shared__ float tA[KC * 64];
    __shared__ float tB2[KC * 64];
    __shared__ float part[4][6][64];
    __shared__ float sm[8 * 64];
    __shared__ int sx[8 * 64];
    __shared__ float shA[ACTN];
    __shared__ int shI[S];

    for (int t = 0; t < T; ++t) {
        const float* dPrev = (t & 1) ? dB : dA;
        float* dNext = (t & 1) ? dA : dB;

        // ================= stage A =================
        if (bid < 256) {
            int b = bid;
            if (tid < ACTN) shA[tid] = act[((size_t)b * T + t) * ACTN + tid];
            if (t > 0 && tid < S) shI[tid] = idxB[b * S + tid];
            __syncthreads();
            for (int h = tid; h < HID; h += 512) {
                float a = b1[h];
#pragma unroll
                for (int k = 0; k < ACTN; ++k) a += shA[k] * W1[(size_t)(SFN + k) * HID + h];
                if (t > 0) {
#pragma unroll 8
                    for (int s = 0; s < S; ++s) a += W1[(size_t)(s * DD + shI[s]) * HID + h];
                }
                xT[(size_t)h * B + b] = elu1(a);
            }
        }
        gridBar(bar, t * 4 + 0, nblk);

        // ================= stage B (GRU) =================
        if (bcActive) {
            int jp = ws & 3;        // j-pair slot: j = jg*8 + 2*jp (+1)
            int kq = ws >> 2;       // 0: x-part, 1: d-part
            int jpG = jg * 4 + jp;  // global pair id
            const float* w = WB2 + ((size_t)jpG * 1200 + kq * 600) * 6;
            float a00 = 0, a01 = 0, a02 = 0, a10 = 0, a11 = 0, a12 = 0;
            for (int c = 0; c < 600; c += KC) {
                __syncthreads();
                for (int i = tid; i < KC * 16 * 2; i += 512) {
                    int hf = i >= KC * 16;
                    int i2 = hf ? i - KC * 16 : i;
                    int kk = i2 >> 4, qq = (i2 & 15) << 2;
                    float4 v = *(const float4*)((hf ? dPrev : xT) + (size_t)(c + kk) * B + b0BC + qq);
                    float* d = (hf ? tB2 : tA) + kk * 64 + qq;
                    d[0] = v.x; d[1] = v.y; d[2] = v.z; d[3] = v.w;
                }
                __syncthreads();
                const float* tl = kq ? tB2 : tA;
                const float* wc = w + (size_t)c * 6;
#pragma unroll 4
                for (int kk = 0; kk < KC; ++kk) {
                    float x = tl[kk * 64 + lane];
                    const float* wk = wc + kk * 6;
                    float2 u0 = *(const float2*)(wk);
                    float2 u1 = *(const float2*)(wk + 2);
                    float2 u2 = *(const float2*)(wk + 4);
                    a00 += x * u0.x; a01 += x * u0.y; a02 += x * u1.x;
                    a10 += x * u1.y; a11 += x * u2.x; a12 += x * u2.y;
                }
            }
            __syncthreads();
            if (kq) {
                part[jp][0][lane] = a00; part[jp][1][lane] = a01; part[jp][2][lane] = a02;
                part[jp][3][lane] = a10; part[jp][4][lane] = a11; part[jp][5][lane] = a12;
            }
            __syncthreads();
            if (!kq) {
                int b = b0BC + lane;
#pragma unroll
                for (int e = 0; e < 2; ++e) {
                    int jj = jg * 8 + 2 * jp + e;
                    float az = (e ? a10 : a00) + part[jp][e * 3 + 0][lane];
                    float ar = (e ? a11 : a01) + part[jp][e * 3 + 1][lane];
                    float ax = (e ? a12 : a02);
                    float ah = part[jp][e * 3 + 2][lane];
                    float dp = dPrev[(size_t)jj * B + b];
                    float z = sigm(az + b_in[jj] + b_rec[jj]);
                    float rr = sigm(ar + b_in[600 + jj] + b_rec[600 + jj]);
                    float cand = tanhf(ax + b_in[1200 + jj] + rr * (ah + b_rec[1200 + jj]));
                    float dn = z * dp + (1.f - z) * cand;
                    dNext[(size_t)jj * B + b] = dn;
                    out[((size_t)b * T + t) * OUTF + 2 * SFN + jj] = dn;
                }
            }
        }
        gridBar(bar, t * 4 + 1, nblk);

        // ================= stage C =================
        if (bcActive) {
            int j0 = jg * 16 + 2 * ws;   // j-pair per wave
            const float* wcBase = WC2 + (size_t)(jg * 8 + ws) * 600 * 2;
            float a0 = 0, a1 = 0;
            for (int c = 0; c < 600; c += KC) {
                __syncthreads();
                for (int i = tid; i < KC * 16; i += 512) {
                    int kk = i >> 4, qq = (i & 15) << 2;
                    float4 v = *(const float4*)(dNext + (size_t)(c + kk) * B + b0BC + qq);
                    float* d = tA + kk * 64 + qq;
                    d[0] = v.x; d[1] = v.y; d[2] = v.z; d[3] = v.w;
                }
                __syncthreads();
                const float* wc = wcBase + (size_t)c * 2;
#pragma unroll 4
                for (int kk = 0; kk < KC; ++kk) {
                    float x = tA[kk * 64 + lane];
                    float2 u = *(const float2*)(wc + kk * 2);
                    a0 += x * u.x; a1 += x * u.y;
                }
            }
            int b = b0BC + lane;
            if (j0 < 600) {
                yoT[(size_t)j0 * B + b] = elu1(a0 + b2[j0]);
                yoT[(size_t)(j0 + 1) * B + b] = elu1(a1 + b2[j0 + 1]);
            } else {
                int je = j0 - 600;
                yoT[(size_t)j0 * B + b] = elu1(a0 + embPre[((size_t)t * 600 + je) * B + b]);
                yoT[(size_t)(j0 + 1) * B + b] = elu1(a1 + embPre[((size_t)t * 600 + je + 1) * B + b]);
            }
        }
        gridBar(bar, t * 4 + 2, nblk);

        // ================= stage D =================
        if (dActive) {
            int dloc = ws * 4;
            int jglob = postD * SFN + sD * DD + dloc;
            const float* src = yoT + (postD ? (size_t)600 * B : 0);
            const float* w0 = WDm + (size_t)jglob * 600;
            const float* w1 = w0 + 600;
            const float* w2 = w0 + 1200;
            const float* w3 = w0 + 1800;
            float a0 = 0, a1 = 0, a2 = 0, a3 = 0;
            for (int c = 0; c < 600; c += KC) {
                __syncthreads();
                for (int i = tid; i < KC * 16; i += 512) {
                    int kk = i >> 4, qq = (i & 15) << 2;
                    float4 v = *(const float4*)(src + (size_t)(c + kk) * B + b0D + qq);
                    float* d = tA + kk * 64 + qq;
                    d[0] = v.x; d[1] = v.y; d[2] = v.z; d[3] = v.w;
                }
                __syncthreads();
#pragma unroll 2
                for (int kk = 0; kk < KC; kk += 4) {
                    float4 p0 = *(const float4*)(w0 + c + kk);
                    float4 p1 = *(const float4*)(w1 + c + kk);
                    float4 p2 = *(const float4*)(w2 + c + kk);
                    float4 p3 = *(const float4*)(w3 + c + kk);
                    float v0 = tA[(kk + 0) * 64 + lane];
                    float v1 = tA[(kk + 1) * 64 + lane];
                    float v2 = tA[(kk + 2) * 64 + lane];
                    float v3 = tA[(kk + 3) * 64 + lane];
                    a0 += v0 * p0.x + v1 * p0.y + v2 * p0.z + v3 * p0.w;
                    a1 += v0 * p1.x + v1 * p1.y + v2 * p1.z + v3 * p1.w;
                    a2 += v0 * p2.x + v1 * p2.y + v2 * p2.z + v3 * p2.w;
                    a3 += v0 * p3.x + v1 * p3.y + v2 * p3.z + v3 * p3.w;
                }
            }
            int b = b0D + lane;
            const float* bias = postD ? (bo3 + sD * DD) : (b5 + sD * DD);
            const float* g = (postD ? gObs : gImg) + ((size_t)b * T + t) * SFN + sD * DD;
            size_t obase = ((size_t)b * T + t) * OUTF;
            size_t lbase = obase + (postD ? 0 : (2 * SFN + DET)) + sD * DD;
            float vals[4];
            float accs[4] = {a0, a1, a2, a3};
#pragma unroll
            for (int c = 0; c < 4; ++c) {
                float lg = accs[c] + bias[dloc + c];
                out[lbase + dloc + c] = lg;
                vals[c] = lg + g[dloc + c];
            }
            float bm = vals[0];
            int bi = dloc;
#pragma unroll
            for (int c = 1; c < 4; ++c)
                if (vals[c] > bm) { bm = vals[c]; bi = dloc + c; }
            __syncthreads();
            sm[ws * 64 + lane] = bm;
            sx[ws * 64 + lane] = bi;
            __syncthreads();
            float best = sm[lane];
            int bd = sx[lane];
#pragma unroll
            for (int w = 1; w < 8; ++w) {
                float v = sm[w * 64 + lane];
                if (v > best) { best = v; bd = sx[w * 64 + lane]; }
            }
            size_t sbase = obase + (postD ? SFN : (3 * SFN + DET)) + sD * DD;
#pragma unroll
            for (int c = 0; c < 4; ++c)
                out[sbase + dloc + c] = (dloc + c == bd) ? 1.f : 0.f;
            if (postD && ws == 0) idxB[b * S + sD] = bd;
        }
        gridBar(bar, t * 4 + 3, nblk);
    }
}

}  // namespace

extern "C" void kernel_launch(void* const* d_in, const int* in_sizes, int n_in,
                              void* d_out, int out_size, void* d_ws, size_t ws_size,
                              hipStream_t stream) {
    const float* action = (const float*)d_in[0];
    const float* embed  = (const float*)d_in[1];
    const float* gImg   = (const float*)d_in[2];
    const float* gObs   = (const float*)d_in[3];
    const float* W1     = (const float*)d_in[4];
    const float* b1     = (const float*)d_in[5];
    const float* Wx     = (const float*)d_in[6];
    const float* Wh     = (const float*)d_in[7];
    const float* b_in   = (const float*)d_in[8];
    const float* b_rec  = (const float*)d_in[9];
    const float* W2     = (const float*)d_in[10];
    const float* b2     = (const float*)d_in[11];
    const float* W5     = (const float*)d_in[12];
    const float* b5     = (const float*)d_in[13];
    const float* Wo1    = (const float*)d_in[14];
    const float* bo1    = (const float*)d_in[15];
    const float* Wo3    = (const float*)d_in[16];
    const float* bo3    = (const float*)d_in[17];
    float* out = (float*)d_out;

    float* ws = (float*)d_ws;
    float* WB2    = ws;                  // 300*1200*6 = 2,160,000 f
    float* WC2    = WB2 + 2160000;       // 600*600*2  =   720,000 f
    float* WDm    = WC2 + 720000;        // 2048*600   = 1,228,800 f
    float* embPre = WDm + 1228800;       // 64*600*256 = 9,830,400 f
    float* xT     = embPre + 9830400;    // 600*256
    float* dA     = xT + 153600;
    float* dB     = dA + 153600;
    float* yoT    = dB + 153600;         // 1200*256
    int*   idxB   = (int*)(yoT + 307200);
    unsigned* bar = (unsigned*)(idxB + 8192);   // 256 barrier slots

    hipMemsetAsync(dA, 0, 153600 * sizeof(float), stream);     // deter0 = zeros
    hipMemsetAsync(bar, 0, 256 * sizeof(unsigned), stream);    // barrier slots
    kWB2<<<300, 256, 0, stream>>>(Wx, Wh, WB2);
    kWC2<<<600, 256, 0, stream>>>(W2, Wo1, WC2);
    kWD<<<600, 256, 0, stream>>>(W5, Wo3, WDm);
    kPemb<<<2560, 512, 0, stream>>>(embed, Wo1, bo1, embPre);

    kMain<<<320, 512, 0, stream>>>(action, W1, b1,
                                   WB2, b_in, b_rec,
                                   WC2, b2, embPre,
                                   WDm, b5, bo3,
                                   gImg, gObs,
                                   xT, dA, dB, yoT, idxB, bar, out);
}